// Round 2
// baseline (4653.857 us; speedup 1.0000x reference)
//
#include <hip/hip_runtime.h>
#include <hip/hip_bf16.h>

#define DIV_UP(a,b) (((a)+(b)-1)/(b))

typedef __hip_bfloat16 bf16;
__device__ __forceinline__ float b2f(bf16 v) { return __bfloat162float(v); }
__device__ __forceinline__ bf16  f2b(float v) { return __float2bfloat16(v); }
__device__ __forceinline__ void cvt_store(float v, bf16* p)  { *p = f2b(v); }
__device__ __forceinline__ void cvt_store(float v, float* p) { *p = v; }

// ---------------------------------------------------------------------------
// copy fp32 src [N,C,H,W] into bf16 dst slot of a concat buffer
// ---------------------------------------------------------------------------
__global__ __launch_bounds__(256) void copy_cat(
    const float* __restrict__ src, bf16* __restrict__ dst,
    int C, int HW, int dst_nstride, int total)
{
    int idx = blockIdx.x * 256 + threadIdx.x;
    if (idx >= total) return;           // total = N*C*HW
    int n = idx / (C * HW);
    int r = idx - n * (C * HW);
    dst[(size_t)n * dst_nstride + r] = f2b(src[idx]);
}

// ---------------------------------------------------------------------------
// backward_warp(frame fp32 [N,C,H,W], flow fp32 [N,2,H,W]) -> bf16 dst slot.
// x = clamp(j + fx*W/(W-1), 0, W-1), bilinear, border padding.
// ---------------------------------------------------------------------------
__global__ __launch_bounds__(256) void warp_cat(
    const float* __restrict__ frame, const float* __restrict__ flow,
    bf16* __restrict__ dst, int C, int H, int W, int dst_nstride, int total)
{
    int idx = blockIdx.x * 256 + threadIdx.x;
    if (idx >= total) return;           // total = N*H*W
    int HW = H * W;
    int n = idx / HW;
    int r = idx - n * HW;
    int i = r / W;
    int j = r - i * W;

    float fx = flow[((size_t)n * 2 + 0) * HW + r];
    float fy = flow[((size_t)n * 2 + 1) * HW + r];
    float x = (float)j + fx * ((float)W / (float)(W - 1));
    float y = (float)i + fy * ((float)H / (float)(H - 1));
    x = fminf(fmaxf(x, 0.f), (float)(W - 1));
    y = fminf(fmaxf(y, 0.f), (float)(H - 1));
    float x0f = floorf(x), y0f = floorf(y);
    int ix0 = (int)x0f, iy0 = (int)y0f;
    int ix1 = ix0 + 1; if (ix1 > W - 1) ix1 = W - 1;
    int iy1 = iy0 + 1; if (iy1 > H - 1) iy1 = H - 1;
    float wx = x - x0f, wy = y - y0f;
    float w00 = (1.f - wx) * (1.f - wy);
    float w01 = wx * (1.f - wy);
    float w10 = (1.f - wx) * wy;
    float w11 = wx * wy;
    int a00 = iy0 * W + ix0, a01 = iy0 * W + ix1;
    int a10 = iy1 * W + ix0, a11 = iy1 * W + ix1;

    const float* fb = frame + (size_t)n * C * HW;
    bf16* db = dst + (size_t)n * dst_nstride + r;
    for (int c = 0; c < C; ++c) {
        const float* p = fb + (size_t)c * HW;
        db[(size_t)c * HW] = f2b(w00 * p[a00] + w01 * p[a01] + w10 * p[a10] + w11 * p[a11]);
    }
}

// ---------------------------------------------------------------------------
// conv3x3 stride 1, pad 1, bf16 in, OutT out. 256 threads -> 32x32 tile, 8 co.
// ---------------------------------------------------------------------------
template<typename OutT>
__global__ __launch_bounds__(256) void conv3x3_s1(
    const bf16* __restrict__ in, const float* __restrict__ wgt,
    const float* __restrict__ bias, OutT* __restrict__ out,
    int Cin, int H, int W, int Cout, int out_nstride, int relu)
{
    __shared__ float tile[34][36];
    int tiles_x = DIV_UP(W, 32);
    int tx0 = (blockIdx.x % tiles_x) * 32;
    int ty0 = (blockIdx.x / tiles_x) * 32;
    int cob = blockIdx.y * 8;
    int n = blockIdx.z;
    int tid = threadIdx.x;
    int lx = tid & 15, ly = tid >> 4;

    float acc[8][2][2];
#pragma unroll
    for (int o = 0; o < 8; ++o)
#pragma unroll
        for (int r = 0; r < 2; ++r)
#pragma unroll
            for (int c = 0; c < 2; ++c) acc[o][r][c] = 0.f;

    const bf16* inN = in + (size_t)n * Cin * H * W;
    for (int ci = 0; ci < Cin; ++ci) {
        const bf16* src = inN + (size_t)ci * H * W;
        for (int k = tid; k < 34 * 34; k += 256) {
            int r = k / 34, c = k - r * 34;
            int gi = ty0 - 1 + r, gj = tx0 - 1 + c;
            float v = 0.f;
            if ((unsigned)gi < (unsigned)H && (unsigned)gj < (unsigned)W)
                v = b2f(src[gi * W + gj]);
            tile[r][c] = v;
        }
        __syncthreads();

        float p[4][4];
#pragma unroll
        for (int r = 0; r < 4; ++r)
#pragma unroll
            for (int c = 0; c < 4; ++c)
                p[r][c] = tile[2 * ly + r][2 * lx + c];

        const float* wp = wgt + ((size_t)cob * Cin + ci) * 9;
#pragma unroll
        for (int o = 0; o < 8; ++o) {
            if (cob + o < Cout) {
                const float* w9 = wp + (size_t)o * Cin * 9;
                float w0 = w9[0], w1 = w9[1], w2 = w9[2];
                float w3 = w9[3], w4 = w9[4], w5 = w9[5];
                float w6 = w9[6], w7 = w9[7], w8 = w9[8];
#pragma unroll
                for (int r = 0; r < 2; ++r)
#pragma unroll
                    for (int c = 0; c < 2; ++c) {
                        acc[o][r][c] += w0 * p[r][c]     + w1 * p[r][c + 1]     + w2 * p[r][c + 2]
                                      + w3 * p[r + 1][c] + w4 * p[r + 1][c + 1] + w5 * p[r + 1][c + 2]
                                      + w6 * p[r + 2][c] + w7 * p[r + 2][c + 1] + w8 * p[r + 2][c + 2];
                    }
            }
        }
        __syncthreads();
    }

#pragma unroll
    for (int o = 0; o < 8; ++o) {
        int co = cob + o;
        if (co < Cout) {
            float bv = bias[co];
#pragma unroll
            for (int r = 0; r < 2; ++r)
#pragma unroll
                for (int c = 0; c < 2; ++c) {
                    int oi = ty0 + 2 * ly + r, oj = tx0 + 2 * lx + c;
                    if (oi < H && oj < W) {
                        float v = acc[o][r][c] + bv;
                        if (relu) v = fmaxf(v, 0.f);
                        cvt_store(v, &out[(size_t)n * out_nstride + (size_t)co * H * W + oi * W + oj]);
                    }
                }
        }
    }
}

// ---------------------------------------------------------------------------
// conv3x3 stride 2, pad 1, bf16 in/out. 256 threads -> 16x16 out tile, 8 co.
// ---------------------------------------------------------------------------
__global__ __launch_bounds__(256) void conv3x3_s2(
    const bf16* __restrict__ in, const float* __restrict__ wgt,
    const float* __restrict__ bias, bf16* __restrict__ out,
    int Cin, int Hin, int Win, int Cout, int Hout, int Wout, int relu)
{
    __shared__ float tile[33][34];
    int tiles_x = DIV_UP(Wout, 16);
    int tx0 = (blockIdx.x % tiles_x) * 16;
    int ty0 = (blockIdx.x / tiles_x) * 16;
    int cob = blockIdx.y * 8;
    int n = blockIdx.z;
    int tid = threadIdx.x;
    int lx = tid & 15, ly = tid >> 4;

    float acc[8];
#pragma unroll
    for (int o = 0; o < 8; ++o) acc[o] = 0.f;

    const bf16* inN = in + (size_t)n * Cin * Hin * Win;
    for (int ci = 0; ci < Cin; ++ci) {
        const bf16* src = inN + (size_t)ci * Hin * Win;
        for (int k = tid; k < 33 * 33; k += 256) {
            int r = k / 33, c = k - r * 33;
            int gi = 2 * ty0 - 1 + r, gj = 2 * tx0 - 1 + c;
            float v = 0.f;
            if ((unsigned)gi < (unsigned)Hin && (unsigned)gj < (unsigned)Win)
                v = b2f(src[gi * Win + gj]);
            tile[r][c] = v;
        }
        __syncthreads();

        float p[3][3];
#pragma unroll
        for (int r = 0; r < 3; ++r)
#pragma unroll
            for (int c = 0; c < 3; ++c)
                p[r][c] = tile[2 * ly + r][2 * lx + c];

        const float* wp = wgt + ((size_t)cob * Cin + ci) * 9;
#pragma unroll
        for (int o = 0; o < 8; ++o) {
            if (cob + o < Cout) {
                const float* w9 = wp + (size_t)o * Cin * 9;
#pragma unroll
                for (int r = 0; r < 3; ++r)
#pragma unroll
                    for (int c = 0; c < 3; ++c)
                        acc[o] += w9[r * 3 + c] * p[r][c];
            }
        }
        __syncthreads();
    }

    int oi = ty0 + ly, oj = tx0 + lx;
    if (oi < Hout && oj < Wout) {
#pragma unroll
        for (int o = 0; o < 8; ++o) {
            int co = cob + o;
            if (co < Cout) {
                float v = acc[o] + bias[co];
                if (relu) v = fmaxf(v, 0.f);
                out[((size_t)n * Cout + co) * Hout * Wout + oi * Wout + oj] = f2b(v);
            }
        }
    }
}

// ---------------------------------------------------------------------------
// 2x bilinear upsample (half-pixel) of virtual concat [s0 (C0) | s1 (C1)],
// bf16 -> bf16 contiguous [N, C0+C1, 2Hs, 2Ws].
// ---------------------------------------------------------------------------
__global__ __launch_bounds__(256) void up2x_cat(
    const bf16* __restrict__ s0, int C0, long s0_nstride,
    const bf16* __restrict__ s1, int C1, long s1_nstride,
    int Hs, int Ws, bf16* __restrict__ out, int total)
{
    int idx = blockIdx.x * 256 + threadIdx.x;
    if (idx >= total) return;
    int Wo = 2 * Ws, Ho = 2 * Hs;
    int C = C0 + C1;
    int j = idx % Wo;
    int t = idx / Wo;
    int i = t % Ho; t /= Ho;
    int c = t % C;
    int n = t / C;

    const bf16* src;
    if (c < C0) src = s0 + (size_t)n * s0_nstride + (size_t)c * Hs * Ws;
    else        src = s1 + (size_t)n * s1_nstride + (size_t)(c - C0) * Hs * Ws;

    float xs = ((float)j + 0.5f) * 0.5f - 0.5f;
    float ys = ((float)i + 0.5f) * 0.5f - 0.5f;
    float x0f = floorf(xs), y0f = floorf(ys);
    float wx = xs - x0f, wy = ys - y0f;
    int ix0 = (int)x0f, iy0 = (int)y0f;
    int ix1 = ix0 + 1, iy1 = iy0 + 1;
    if (ix0 < 0) ix0 = 0;
    if (iy0 < 0) iy0 = 0;
    if (ix1 > Ws - 1) ix1 = Ws - 1;
    if (iy1 > Hs - 1) iy1 = Hs - 1;

    float v00 = b2f(src[iy0 * Ws + ix0]), v01 = b2f(src[iy0 * Ws + ix1]);
    float v10 = b2f(src[iy1 * Ws + ix0]), v11 = b2f(src[iy1 * Ws + ix1]);
    out[idx] = f2b((1.f - wx) * (1.f - wy) * v00 + wx * (1.f - wy) * v01
                 + (1.f - wx) * wy * v10 + wx * wy * v11);
}

// ---------------------------------------------------------------------------
extern "C" void kernel_launch(void* const* d_in, const int* in_sizes, int n_in,
                              void* d_out, int out_size, void* d_ws, size_t ws_size,
                              hipStream_t stream)
{
    const float* img0  = (const float*)d_in[0];
    const float* img1  = (const float*)d_in[1];
    const float* ft0   = (const float*)d_in[2];
    const float* ft1   = (const float*)d_in[3];
    const float* ft0s2 = (const float*)d_in[4];
    const float* ft1s2 = (const float*)d_in[5];
    const float* ft0s4 = (const float*)d_in[6];
    const float* ft1s4 = (const float*)d_in[7];
    const float* c0_0  = (const float*)d_in[8];
    const float* c0_1  = (const float*)d_in[9];
    const float* c0_2  = (const float*)d_in[10];
    const float* c1_0  = (const float*)d_in[11];
    const float* c1_1  = (const float*)d_in[12];
    const float* c1_2  = (const float*)d_in[13];
    const float* wd0a = (const float*)d_in[14]; const float* bd0a = (const float*)d_in[15];
    const float* wd0b = (const float*)d_in[16]; const float* bd0b = (const float*)d_in[17];
    const float* wd1a = (const float*)d_in[18]; const float* bd1a = (const float*)d_in[19];
    const float* wd1b = (const float*)d_in[20]; const float* bd1b = (const float*)d_in[21];
    const float* wd2a = (const float*)d_in[22]; const float* bd2a = (const float*)d_in[23];
    const float* wd2b = (const float*)d_in[24]; const float* bd2b = (const float*)d_in[25];
    const float* wu0  = (const float*)d_in[26]; const float* bu0  = (const float*)d_in[27];
    const float* wu1  = (const float*)d_in[28]; const float* bu1  = (const float*)d_in[29];
    const float* wu2  = (const float*)d_in[30]; const float* bu2  = (const float*)d_in[31];
    const float* wfin = (const float*)d_in[32]; const float* bfin = (const float*)d_in[33];

    const int HW384 = 384 * 384;   // 147456
    const int HW192 = 192 * 192;   // 36864
    const int HW96  = 96 * 96;     // 9216
    const int HW48  = 48 * 48;     // 2304

    bf16* ws = (bf16*)d_ws;
    // Tight lifetime plan (bf16 elements; total 79,036,416 elems = 158 MB):
    //   s0in @ 0          (41287680)   dead after d0a
    //   t0   @ 41287680   ( 4718592)   dead after d0b
    //   s1in @ 0          (18874368)   ch0-31 (s0) live until up2 concat
    //   t1   @ 18874368   ( 2359296)   dead after d1b
    //   s2in @ 21233664   ( 7077888)   ch0-63 (s1) live until up1 concat
    //   t2   @ 28311552   (  884736)   dead after d2b
    //   s2b  @ 29196288   (  884736)   dead after up0
    //   up0  @ 30081024   ( 3538944)   dead after conv u0
    //   x0   @ 33619968   ( 2359296)   dead after up1 concat
    //   up1  @ 35979264   (18874368)   dead after conv u1
    //   x1   @ 18874368   ( 4718592)   dead after up2 concat
    //   up2  @ 41287680   (37748736)   dead after conv u2
    //   x2   @ 0          (41287680)   dead after final conv
    bf16* s0in = ws + 0;
    bf16* t0   = ws + 41287680;
    bf16* s1in = ws + 0;
    bf16* t1   = ws + 18874368;
    bf16* s2in = ws + 21233664;
    bf16* t2   = ws + 28311552;
    bf16* s2b  = ws + 29196288;
    bf16* up0  = ws + 30081024;
    bf16* x0   = ws + 33619968;
    bf16* up1  = ws + 35979264;
    bf16* x1   = ws + 18874368;
    bf16* up2  = ws + 41287680;
    bf16* x2   = ws + 0;

    // ---- stage 0 input: [img0 | img1 | warp(c0_0,ft0) | warp(c1_0,ft1)] (70 ch @384²)
    copy_cat<<<DIV_UP(4 * 3 * HW384, 256), 256, 0, stream>>>(img0, s0in + 0 * HW384, 3, HW384, 70 * HW384, 4 * 3 * HW384);
    copy_cat<<<DIV_UP(4 * 3 * HW384, 256), 256, 0, stream>>>(img1, s0in + 3 * HW384, 3, HW384, 70 * HW384, 4 * 3 * HW384);
    warp_cat<<<DIV_UP(4 * HW384, 256), 256, 0, stream>>>(c0_0, ft0, s0in + 6 * HW384, 32, 384, 384, 70 * HW384, 4 * HW384);
    warp_cat<<<DIV_UP(4 * HW384, 256), 256, 0, stream>>>(c1_0, ft1, s0in + 38 * HW384, 32, 384, 384, 70 * HW384, 4 * HW384);

    // ---- down0
    conv3x3_s2<<<dim3(12 * 12, 4, 4), 256, 0, stream>>>(s0in, wd0a, bd0a, t0, 70, 384, 384, 32, 192, 192, 1);
    conv3x3_s1<<<dim3(6 * 6, 4, 4), 256, 0, stream>>>(t0, wd0b, bd0b, s1in, 32, 192, 192, 32, 128 * HW192, 1);  // s0 -> s1in ch0-31

    // ---- stage 1 input warps (ch 32-79, 80-127 @192²)
    warp_cat<<<DIV_UP(4 * HW192, 256), 256, 0, stream>>>(c0_1, ft0s2, s1in + 32 * HW192, 48, 192, 192, 128 * HW192, 4 * HW192);
    warp_cat<<<DIV_UP(4 * HW192, 256), 256, 0, stream>>>(c1_1, ft1s2, s1in + 80 * HW192, 48, 192, 192, 128 * HW192, 4 * HW192);

    // ---- down1
    conv3x3_s2<<<dim3(6 * 6, 8, 4), 256, 0, stream>>>(s1in, wd1a, bd1a, t1, 128, 192, 192, 64, 96, 96, 1);
    conv3x3_s1<<<dim3(3 * 3, 8, 4), 256, 0, stream>>>(t1, wd1b, bd1b, s2in, 64, 96, 96, 64, 192 * HW96, 1);    // s1 -> s2in ch0-63

    // ---- stage 2 input warps (ch 64-127, 128-191 @96²)
    warp_cat<<<DIV_UP(4 * HW96, 256), 256, 0, stream>>>(c0_2, ft0s4, s2in + 64 * HW96, 64, 96, 96, 192 * HW96, 4 * HW96);
    warp_cat<<<DIV_UP(4 * HW96, 256), 256, 0, stream>>>(c1_2, ft1s4, s2in + 128 * HW96, 64, 96, 96, 192 * HW96, 4 * HW96);

    // ---- down2
    conv3x3_s2<<<dim3(3 * 3, 12, 4), 256, 0, stream>>>(s2in, wd2a, bd2a, t2, 192, 96, 96, 96, 48, 48, 1);
    conv3x3_s1<<<dim3(2 * 2, 12, 4), 256, 0, stream>>>(t2, wd2b, bd2b, s2b, 96, 48, 48, 96, 96 * HW48, 1);     // s2

    // ---- decoder (inner relu before each conv is a no-op: inputs all >= 0)
    up2x_cat<<<DIV_UP(4 * 96 * HW96, 256), 256, 0, stream>>>(s2b, 96, 96L * HW48, (const bf16*)nullptr, 0, 0L, 48, 48, up0, 4 * 96 * HW96);
    conv3x3_s1<<<dim3(3 * 3, 8, 4), 256, 0, stream>>>(up0, wu0, bu0, x0, 96, 96, 96, 64, 64 * HW96, 1);

    up2x_cat<<<DIV_UP(4 * 128 * HW192, 256), 256, 0, stream>>>(x0, 64, 64L * HW96, s2in, 64, 192L * HW96, 96, 96, up1, 4 * 128 * HW192);
    conv3x3_s1<<<dim3(6 * 6, 4, 4), 256, 0, stream>>>(up1, wu1, bu1, x1, 128, 192, 192, 32, 32 * HW192, 1);

    up2x_cat<<<DIV_UP(4 * 64 * HW384, 256), 256, 0, stream>>>(x1, 32, 32L * HW192, s1in, 32, 128L * HW192, 192, 192, up2, 4 * 64 * HW384);
    conv3x3_s1<<<dim3(12 * 12, 9, 4), 256, 0, stream>>>(up2, wu2, bu2, x2, 64, 384, 384, 70, 70 * HW384, 1);

    // ---- final conv (no relu), fp32 out
    conv3x3_s1<<<dim3(12 * 12, 1, 4), 256, 0, stream>>>(x2, wfin, bfin, (float*)d_out, 70, 384, 384, 4, 4 * HW384, 0);
}